// Round 1
// baseline (239.087 us; speedup 1.0000x reference)
//
#include <hip/hip_runtime.h>

// Problem constants (match reference)
#define BATCHN 32
#define NCELL  4096
#define BN     (BATCHN * NCELL)

// Chunked-halo time blocking:
//  - each block owns OWN cells of one row, loads OWN + 2*HALO cells,
//    advances KSTEP (<= HALO) timesteps locally in LDS, writes owned cells
//    of every intermediate step to the trajectory output.
constexpr int OWN    = 512;
constexpr int HALO   = 64;
constexpr int CELLS  = OWN + 2 * HALO;   // 640
constexpr int NTHR   = CELLS / 2;        // 320 threads, 2 cells/thread
constexpr int KSTEP  = 60;               // steps per launch (<= HALO)
constexpr int CHUNKS = NCELL / OWN;      // 8

// f(u) and |f'(u)| exactly as the reference's f_real + jvp derivative:
//   f  = 0.5*u*(3-u^2) + (10/12)*u^2*g,   g  = 0.75 - 2u + 1.5u^2 - 0.25u^4
//   f' = (1.5 - 1.5u^2) + (10/12)*(2u*g + u^2*g'),  g' = -2 + 3u - u^3
__device__ __forceinline__ void f_and_a(float u, float& f, float& a) {
    const float C56 = 0.8333333333333333f;  // 10/12 rounded to f32
    float u2 = u * u;
    float u4 = u2 * u2;
    float g  = 0.75f - 2.0f * u + 1.5f * u2 - 0.25f * u4;
    f = 0.5f * u * (3.0f - u2) + C56 * (u2 * g);
    float gp = -2.0f + 3.0f * u - u2 * u;
    float df = (1.5f - 1.5f * u2) + C56 * (2.0f * u * g + u2 * gp);
    a = fabsf(df);
}

__global__ __launch_bounds__(NTHR) void lf_chunk(const float* __restrict__ in_state,
                                                 float* __restrict__ out,
                                                 int s0, int nsteps) {
    // parity double-buffered LDS: one __syncthreads() per step suffices
    __shared__ float su[2][CELLS];
    __shared__ float sf[2][CELLS];
    __shared__ float sa[2][CELLS];

    const int tid   = threadIdx.x;
    const int chunk = blockIdx.x;
    const int row   = blockIdx.y;
    const int gbase = chunk * OWN - HALO;   // local c -> global gbase + c
    const int c0    = tid * 2;
    const bool isLeft  = (chunk == 0);
    const bool isRight = (chunk == CHUNKS - 1);

    const float dtdx = (float)(0.0009 / (10.0 / 4096.0));

    // ---- load chunk + halo (clamped at physical edges) ----
    float uc0, uc1;
    {
        int g0 = gbase + c0;
        int g1 = g0 + 1;
        g0 = min(max(g0, 0), NCELL - 1);
        g1 = min(max(g1, 0), NCELL - 1);
        const float* ip = in_state + (size_t)row * NCELL;
        uc0 = ip[g0];
        uc1 = ip[g1];
        su[0][c0]     = uc0;
        su[0][c0 + 1] = uc1;
    }

    const bool owned = (c0 >= HALO) && (c0 < HALO + OWN);
    float* op = out + (size_t)(s0 + 1) * BN + (size_t)row * NCELL + (gbase + c0);

    const int cl = max(c0 - 1, 0);          // left neighbor (other thread)
    const int cr = min(c0 + 2, CELLS - 1);  // right neighbor (other thread)

    int p = 0;
    for (int t = 0; t < nsteps; ++t) {
        // phase A: f and |f'| for own cells -> LDS (parity p)
        float f0, a0, f1, a1;
        f_and_a(uc0, f0, a0);
        f_and_a(uc1, f1, a1);
        sf[p][c0] = f0;  sf[p][c0 + 1] = f1;
        sa[p][c0] = a0;  sa[p][c0 + 1] = a1;
        __syncthreads();

        // phase B: fluxes + update
        float fl = sf[p][cl], al = sa[p][cl], ul = su[p][cl];
        float fr = sf[p][cr], ar = sa[p][cr], ur = su[p][cr];

        float fh_l = 0.5f * (fl + f0) - 0.5f * fmaxf(al, a0) * (uc0 - ul);
        float fh_m = 0.5f * (f0 + f1) - 0.5f * fmaxf(a0, a1) * (uc1 - uc0);
        float fh_r = 0.5f * (f1 + fr) - 0.5f * fmaxf(a1, ar) * (ur - uc1);

        float n0 = uc0 - dtdx * (fh_m - fh_l);
        float n1 = uc1 - dtdx * (fh_r - fh_m);

        // outflow BCs, applied by the thread owning both edge cells
        if (isLeft && c0 == HALO)            n0 = n1;  // global cell 0
        if (isRight && c0 == HALO + OWN - 2) n1 = n0;  // global cell N-1

        int q = p ^ 1;
        su[q][c0]     = n0;
        su[q][c0 + 1] = n1;

        if (owned) {
            *(float2*)op = make_float2(n0, n1);
        }
        op += BN;

        uc0 = n0;
        uc1 = n1;
        p = q;
        // no trailing barrier needed: next iteration's barrier (between
        // phase A and phase B) separates all cross-parity LDS hazards
    }
}

extern "C" void kernel_launch(void* const* d_in, const int* in_sizes, int n_in,
                              void* d_out, int out_size, void* d_ws, size_t ws_size,
                              hipStream_t stream) {
    const float* init = (const float*)d_in[0];
    float* out = (float*)d_out;

    // stepnum is implied by out_size: (stepnum+1)*B*N elements
    const int total = out_size / BN - 1;

    // plane 0 = init
    hipMemcpyAsync(d_out, init, (size_t)BN * sizeof(float),
                   hipMemcpyDeviceToDevice, stream);

    dim3 grid(CHUNKS, BATCHN);
    for (int s = 0; s < total; s += KSTEP) {
        int ns = (total - s) < KSTEP ? (total - s) : KSTEP;
        lf_chunk<<<grid, NTHR, 0, stream>>>(out + (size_t)s * BN, out, s, ns);
    }
}